// Round 3
// baseline (1465.805 us; speedup 1.0000x reference)
//
#include <hip/hip_runtime.h>
#include <math.h>

#define EPSF 1e-5f

// Problem constants
// B=128, C=8, H=144, W=144, CW=1152, R=B*H=18432, TW=5, OG=2, NCLS=6, DT=256, ITC=5760

// ---------------------------------------------------------------------------
// head1: fused gather-GEMM + batchnorm affine
// M = 18432 rows (b*144+hh), K = 1152 (c*144+w), N = 512 (cols 0-255 ext | 256-511 cls)
// h1out[row*512 + o] = ((sum_k w1[o,k]*x'[row,k]) + b1[o] - m[o]) * g[o]/sqrt(v[o]+eps) + bb[o]
// PATCH=1: x' columns in window [a-2, a+2] replaced by refined5 (predicated on *flag)
// ---------------------------------------------------------------------------
template<int PATCH>
__global__ __launch_bounds__(256) void head1_gemm(
    const float* __restrict__ x,
    const float* __restrict__ w1e, const float* __restrict__ w1c,
    const float* __restrict__ b1e, const float* __restrict__ ge, const float* __restrict__ bbe,
    const float* __restrict__ me, const float* __restrict__ ve,
    const float* __restrict__ b1c, const float* __restrict__ gc, const float* __restrict__ bbc,
    const float* __restrict__ mc, const float* __restrict__ vc,
    const int* __restrict__ amax, const float* __restrict__ refined5, const int* __restrict__ flag,
    float* __restrict__ h1out)
{
    __shared__ float As[16][132];
    __shared__ float Ws[16][132];
    const int tid = threadIdx.x;
    const int tx = tid & 15, ty = tid >> 4;
    const int nb = blockIdx.x * 128;   // output col base (0..384)
    const int rb = blockIdx.y * 128;   // row base

    const int fl = PATCH ? *flag : 0;

    float acc[8][8];
#pragma unroll
    for (int i = 0; i < 8; i++)
#pragma unroll
        for (int j = 0; j < 8; j++) acc[i][j] = 0.f;

    for (int kb = 0; kb < 1152; kb += 16) {
        // stage A tile: 128 rows x 16 k, via float4 (16-float chunks never cross a c boundary: 144%16==0)
        for (int e = tid; e < 512; e += 256) {
            int rl = e >> 2, k4 = (e & 3) << 2;
            int row = rb + rl;
            int b = row / 144, hh = row - b * 144;
            int k = kb + k4;
            int c = k / 144, w = k - c * 144;
            const float4 v4 = *reinterpret_cast<const float4*>(x + (((b * 8 + c) * 144 + hh) * 144 + w));
            float vv[4] = {v4.x, v4.y, v4.z, v4.w};
            if (PATCH && fl) {
                int a = amax[row];
                int d0 = w - a + 2;
#pragma unroll
                for (int q = 0; q < 4; q++) {
                    int dw = d0 + q;
                    if (dw >= 0 && dw < 5) vv[q] = refined5[b * 5760 + (c * 144 + hh) * 5 + dw];
                }
            }
#pragma unroll
            for (int q = 0; q < 4; q++) As[k4 + q][rl] = vv[q];
        }
        // stage W tile: 128 outs x 16 k
        for (int e = tid; e < 512; e += 256) {
            int ol = e >> 2, k4 = (e & 3) << 2;
            int o = nb + ol;
            const float* wrow = (o < 256) ? (w1e + (size_t)o * 1152) : (w1c + (size_t)(o - 256) * 1152);
            const float4 v4 = *reinterpret_cast<const float4*>(wrow + kb + k4);
            Ws[k4 + 0][ol] = v4.x; Ws[k4 + 1][ol] = v4.y;
            Ws[k4 + 2][ol] = v4.z; Ws[k4 + 3][ol] = v4.w;
        }
        __syncthreads();
#pragma unroll
        for (int kk = 0; kk < 16; kk++) {
            float a8[8], w8[8];
#pragma unroll
            for (int i = 0; i < 8; i++) a8[i] = As[kk][ty + 16 * i];
#pragma unroll
            for (int j = 0; j < 8; j++) w8[j] = Ws[kk][tx + 16 * j];
#pragma unroll
            for (int i = 0; i < 8; i++)
#pragma unroll
                for (int j = 0; j < 8; j++)
                    acc[i][j] += a8[i] * w8[j];
        }
        __syncthreads();
    }

    // epilogue: batchnorm affine with given stats
    const float *b1p, *gp, *bbp, *mp, *vp; int obase;
    if (nb < 256) { b1p = b1e; gp = ge; bbp = bbe; mp = me; vp = ve; obase = nb; }
    else          { b1p = b1c; gp = gc; bbp = bbc; mp = mc; vp = vc; obase = nb - 256; }
    float sj[8], cj[8];
#pragma unroll
    for (int j = 0; j < 8; j++) {
        int o = obase + tx + 16 * j;
        float s = gp[o] * rsqrtf(vp[o] + EPSF);
        sj[j] = s;
        cj[j] = (b1p[o] - mp[o]) * s + bbp[o];
    }
#pragma unroll
    for (int i = 0; i < 8; i++) {
        int row = rb + ty + 16 * i;
        float* orow = h1out + (size_t)row * 512 + nb;
#pragma unroll
        for (int j = 0; j < 8; j++)
            orow[tx + 16 * j] = acc[i][j] * sj[j] + cj[j];
    }
}

// ---------------------------------------------------------------------------
// cls second GEMM: logits[row,o] = sum_k cls_w2[o,k]*h1[row,256+k] + b2[o]
// M=18432, N=144, K=256.  Tile 64x48, 4x3 per thread.
// ---------------------------------------------------------------------------
__global__ __launch_bounds__(256) void cls2_gemm(
    const float* __restrict__ h1, const float* __restrict__ w2, const float* __restrict__ b2,
    float* __restrict__ logits)
{
    __shared__ float As[16][68];
    __shared__ float Ws[16][52];
    const int tid = threadIdx.x;
    const int tx = tid & 15, ty = tid >> 4;
    const int nb = blockIdx.x * 48;
    const int rb = blockIdx.y * 64;

    float acc[4][3];
#pragma unroll
    for (int i = 0; i < 4; i++)
#pragma unroll
        for (int j = 0; j < 3; j++) acc[i][j] = 0.f;

    for (int kb = 0; kb < 256; kb += 16) {
        { // A: 64x16 = 256 float4, exactly one per thread
            int rl = tid >> 2, k4 = (tid & 3) << 2;
            const float4 v4 = *reinterpret_cast<const float4*>(h1 + (size_t)(rb + rl) * 512 + 256 + kb + k4);
            As[k4 + 0][rl] = v4.x; As[k4 + 1][rl] = v4.y;
            As[k4 + 2][rl] = v4.z; As[k4 + 3][rl] = v4.w;
        }
        if (tid < 192) { // W: 48x16 = 192 float4
            int ol = tid >> 2, k4 = (tid & 3) << 2;
            const float4 v4 = *reinterpret_cast<const float4*>(w2 + (size_t)(nb + ol) * 256 + kb + k4);
            Ws[k4 + 0][ol] = v4.x; Ws[k4 + 1][ol] = v4.y;
            Ws[k4 + 2][ol] = v4.z; Ws[k4 + 3][ol] = v4.w;
        }
        __syncthreads();
#pragma unroll
        for (int kk = 0; kk < 16; kk++) {
            float a4[4], w3[3];
#pragma unroll
            for (int i = 0; i < 4; i++) a4[i] = As[kk][ty + 16 * i];
#pragma unroll
            for (int j = 0; j < 3; j++) w3[j] = Ws[kk][tx + 16 * j];
#pragma unroll
            for (int i = 0; i < 4; i++)
#pragma unroll
                for (int j = 0; j < 3; j++)
                    acc[i][j] += a4[i] * w3[j];
        }
        __syncthreads();
    }
    float bj[3];
#pragma unroll
    for (int j = 0; j < 3; j++) bj[j] = b2[nb + tx + 16 * j];
#pragma unroll
    for (int i = 0; i < 4; i++) {
        int row = rb + ty + 16 * i;
#pragma unroll
        for (int j = 0; j < 3; j++)
            logits[(size_t)row * 144 + nb + tx + 16 * j] = acc[i][j] + bj[j];
    }
}

// ---------------------------------------------------------------------------
// row softmax over 144 (one wave per row) + optional argmax (first-max tie rule)
// ---------------------------------------------------------------------------
__global__ __launch_bounds__(256) void cls_softmax(const float* __restrict__ logits,
                                                   float* __restrict__ outp, int* __restrict__ amax)
{
    int row = blockIdx.x * 4 + (threadIdx.x >> 6);
    int lane = threadIdx.x & 63;
    const float* L = logits + (size_t)row * 144;
    float v0 = L[lane];
    float v1 = L[lane + 64];
    float v2 = (lane < 16) ? L[lane + 128] : -3.0e38f;
    float m = v0; int mi = lane;
    if (v1 > m) { m = v1; mi = lane + 64; }
    if (v2 > m) { m = v2; mi = lane + 128; }
#pragma unroll
    for (int off = 32; off; off >>= 1) {
        float om = __shfl_xor(m, off);
        int   oi = __shfl_xor(mi, off);
        if (om > m || (om == m && oi < mi)) { m = om; mi = oi; }
    }
    float e0 = expf(v0 - m), e1 = expf(v1 - m);
    float e2 = (lane < 16) ? expf(v2 - m) : 0.f;
    float s = e0 + e1 + e2;
#pragma unroll
    for (int off = 32; off; off >>= 1) s += __shfl_xor(s, off);
    float inv = 1.f / s;
    float* O = outp + (size_t)row * 144;
    O[lane] = e0 * inv;
    O[lane + 64] = e1 * inv;
    if (lane < 16) O[lane + 128] = e2 * inv;
    if (amax != nullptr && lane == 0) amax[row] = mi;
}

// ---------------------------------------------------------------------------
// ext head: 2 logits per row + softmax; optional per-block partial sums of p0
// ---------------------------------------------------------------------------
__global__ __launch_bounds__(256) void ext_head(const float* __restrict__ h1,
    const float* __restrict__ w2, const float* __restrict__ b2,
    float* __restrict__ outp, float* __restrict__ partials)
{
    __shared__ float ps[4];
    int row = blockIdx.x * 4 + (threadIdx.x >> 6);
    int lane = threadIdx.x & 63;
    const float* n1 = h1 + (size_t)row * 512;   // ext half = cols 0..255
    float a0 = 0.f, a1 = 0.f;
#pragma unroll
    for (int k = lane; k < 256; k += 64) {
        float z = n1[k];
        a0 += w2[k] * z;
        a1 += w2[256 + k] * z;
    }
#pragma unroll
    for (int off = 32; off; off >>= 1) { a0 += __shfl_xor(a0, off); a1 += __shfl_xor(a1, off); }
    float l0 = a0 + b2[0], l1 = a1 + b2[1];
    float m = fmaxf(l0, l1);
    float e0 = expf(l0 - m), e1 = expf(l1 - m);
    float inv = 1.f / (e0 + e1);
    float p0 = e0 * inv;
    if (lane == 0) { outp[(size_t)row * 2] = p0; outp[(size_t)row * 2 + 1] = e1 * inv; }
    if (partials != nullptr) {
        if (lane == 0) ps[threadIdx.x >> 6] = p0;
        __syncthreads();
        if (threadIdx.x == 0) partials[blockIdx.x] = (ps[0] + ps[1]) + (ps[2] + ps[3]);
    }
}

__global__ __launch_bounds__(256) void reduce_flag(const float* __restrict__ partials, int n,
                                                   int* __restrict__ flag)
{
    __shared__ float sm[256];
    int tid = threadIdx.x;
    float s = 0.f;
    for (int i = tid; i < n; i += 256) s += partials[i];
    sm[tid] = s; __syncthreads();
    for (int off = 128; off; off >>= 1) {
        if (tid < off) sm[tid] += sm[tid + off];
        __syncthreads();
    }
    if (tid == 0) *flag = (sm[0] * (1.f / 18432.f) > 0.3f) ? 1 : 0;
}

// ---------------------------------------------------------------------------
// gather patches from zero-padded x at argmax windows
// patches[b, (c*144+hh)*5+tw] = xpad[b,c,hh, a+tw] = x[b,c,hh, a+tw-2] or 0
// ---------------------------------------------------------------------------
__global__ __launch_bounds__(256) void gather_patches(const float* __restrict__ x,
    const int* __restrict__ amax, float* __restrict__ patches)
{
    int idx = blockIdx.x * 256 + threadIdx.x;   // grid covers exactly 128*5760
    int b = idx / 5760, j = idx - b * 5760;
    int c = j / 720, r2 = j - c * 720;
    int hh = r2 / 5, tw = r2 - hh * 5;
    int a = amax[b * 144 + hh];
    int w = a + tw - 2;
    patches[idx] = (w >= 0 && w < 144) ? x[(((b * 8 + c) * 144 + hh) * 144) + w] : 0.f;
}

// ---------------------------------------------------------------------------
// tok GEMM, K-split into 8 chunks of 720 for parallelism (deterministic 2-stage)
// ---------------------------------------------------------------------------
__global__ __launch_bounds__(256) void tok_partial(const float* __restrict__ patches,
    const float* __restrict__ tok_w, float* __restrict__ tpart)
{
    __shared__ float P[720];
    int b = blockIdx.x, ks = blockIdx.y, tid = threadIdx.x;
    for (int e = tid; e < 720; e += 256) P[e] = patches[(size_t)b * 5760 + ks * 720 + e];
    __syncthreads();
    float acc = 0.f;
    const float* wbase = tok_w + (size_t)ks * 720 * 256;
    for (int k = 0; k < 720; k++) acc += P[k] * wbase[(size_t)k * 256 + tid];
    tpart[((size_t)b * 8 + ks) * 256 + tid] = acc;
}

__global__ __launch_bounds__(256) void tok_finish(const float* __restrict__ tpart,
    const float* __restrict__ tok_b, const float* __restrict__ emb, float* __restrict__ tokens)
{
    int b = blockIdx.x, n = threadIdx.x;
    float s = tok_b[n];
    for (int ks = 0; ks < 8; ks++) s += tpart[((size_t)b * 8 + ks) * 256 + n];
    for (int i = 0; i < 6; i++) tokens[((size_t)b * 6 + i) * 256 + n] = s + emb[i * 256 + n];
}

// ---------------------------------------------------------------------------
// full tiny transformer per batch element (seq=6, dim=256, 2 heads x 32)
// outputs LNF of token 5 only (only refined[:,5] survives the reference scatter)
// ---------------------------------------------------------------------------
__device__ inline void block_sum2(float v1, float v2, float* r8, int tid, float& s1, float& s2)
{
#pragma unroll
    for (int off = 32; off; off >>= 1) { v1 += __shfl_down(v1, off); v2 += __shfl_down(v2, off); }
    int w = tid >> 6;
    if ((tid & 63) == 0) { r8[w * 2] = v1; r8[w * 2 + 1] = v2; }
    __syncthreads();
    s1 = (r8[0] + r8[2]) + (r8[4] + r8[6]);
    s2 = (r8[1] + r8[3]) + (r8[5] + r8[7]);
    __syncthreads();
}

__global__ __launch_bounds__(256) void transformer_kernel(
    const float* __restrict__ tokens,
    const float* __restrict__ ln1_g, const float* __restrict__ ln1_b,
    const float* __restrict__ qkv_w, const float* __restrict__ out_w, const float* __restrict__ out_b,
    const float* __restrict__ ln2_g, const float* __restrict__ ln2_b,
    const float* __restrict__ ff_w1, const float* __restrict__ ff_b1,
    const float* __restrict__ ff_w2, const float* __restrict__ ff_b2,
    const float* __restrict__ lnf_g, const float* __restrict__ lnf_b,
    float* __restrict__ tfin)
{
    __shared__ float t[6][256];
    __shared__ float z[6][256];
    __shared__ float qkv[6][192];
    __shared__ float att[2][6][6];
    __shared__ float o[6][64];
    __shared__ float f[6][512];
    __shared__ float red8[8];

    int b = blockIdx.x, tid = threadIdx.x;
    for (int e = tid; e < 1536; e += 256) t[e >> 8][e & 255] = tokens[(size_t)b * 1536 + e];
    __syncthreads();

    // LN1 -> z
    for (int i = 0; i < 6; i++) {
        float v = t[i][tid];
        float s1, s2; block_sum2(v, v * v, red8, tid, s1, s2);
        float mu = s1 * (1.f / 256.f);
        float var = s2 * (1.f / 256.f) - mu * mu;
        z[i][tid] = (v - mu) * rsqrtf(var + EPSF) * ln1_g[tid] + ln1_b[tid];
    }
    __syncthreads();

    // qkv = z @ qkv_w   (256x192)
    if (tid < 192) {
        float acc[6] = {0.f, 0.f, 0.f, 0.f, 0.f, 0.f};
        for (int k = 0; k < 256; k++) {
            float wv = qkv_w[(size_t)k * 192 + tid];
#pragma unroll
            for (int i = 0; i < 6; i++) acc[i] += z[i][k] * wv;
        }
#pragma unroll
        for (int i = 0; i < 6; i++) qkv[i][tid] = acc[i];
    }
    __syncthreads();

    // attention scores
    if (tid < 72) {
        int h = tid / 36, rem = tid - h * 36, i = rem / 6, j = rem - (rem / 6) * 6;
        float s = 0.f;
#pragma unroll
        for (int d = 0; d < 32; d++) s += qkv[i][h * 32 + d] * qkv[j][64 + h * 32 + d];
        att[h][i][j] = s * 0.17677669529663687f;   // 1/sqrt(32)
    }
    __syncthreads();
    if (tid < 12) {
        int h = tid / 6, i = tid - h * 6;
        float m = -3.0e38f;
        for (int j = 0; j < 6; j++) m = fmaxf(m, att[h][i][j]);
        float s = 0.f;
        for (int j = 0; j < 6; j++) { float e = expf(att[h][i][j] - m); att[h][i][j] = e; s += e; }
        float inv = 1.f / s;
        for (int j = 0; j < 6; j++) att[h][i][j] *= inv;
    }
    __syncthreads();
    // o = att @ v
    for (int e = tid; e < 384; e += 256) {
        int i = e / 64, hd = e - i * 64, h = hd >> 5;
        float s = 0.f;
#pragma unroll
        for (int j = 0; j < 6; j++) s += att[h][i][j] * qkv[j][128 + hd];
        o[i][hd] = s;
    }
    __syncthreads();
    // t += o @ out_w + out_b
    {
        float accs[6];
#pragma unroll
        for (int i = 0; i < 6; i++) {
            float a = out_b[tid];
            for (int d = 0; d < 64; d++) a += o[i][d] * out_w[(size_t)d * 256 + tid];
            accs[i] = a;
        }
#pragma unroll
        for (int i = 0; i < 6; i++) t[i][tid] += accs[i];
    }
    __syncthreads();

    // LN2 -> z
    for (int i = 0; i < 6; i++) {
        float v = t[i][tid];
        float s1, s2; block_sum2(v, v * v, red8, tid, s1, s2);
        float mu = s1 * (1.f / 256.f);
        float var = s2 * (1.f / 256.f) - mu * mu;
        z[i][tid] = (v - mu) * rsqrtf(var + EPSF) * ln2_g[tid] + ln2_b[tid];
    }
    __syncthreads();

    // f = gelu(z @ ff_w1 + ff_b1), exact gelu
    for (int jj = tid; jj < 512; jj += 256) {
        float acc[6] = {0.f, 0.f, 0.f, 0.f, 0.f, 0.f};
        for (int k = 0; k < 256; k++) {
            float wv = ff_w1[(size_t)k * 512 + jj];
#pragma unroll
            for (int i = 0; i < 6; i++) acc[i] += z[i][k] * wv;
        }
#pragma unroll
        for (int i = 0; i < 6; i++) {
            float xx = acc[i] + ff_b1[jj];
            f[i][jj] = 0.5f * xx * (1.f + erff(xx * 0.70710678118654752f));
        }
    }
    __syncthreads();
    // t += f @ ff_w2 + ff_b2
    {
        float a6[6];
#pragma unroll
        for (int i = 0; i < 6; i++) a6[i] = ff_b2[tid];
        for (int k = 0; k < 512; k++) {
            float wv = ff_w2[(size_t)k * 256 + tid];
#pragma unroll
            for (int i = 0; i < 6; i++) a6[i] += f[i][k] * wv;
        }
#pragma unroll
        for (int i = 0; i < 6; i++) t[i][tid] += a6[i];
    }
    __syncthreads();

    // LNF of token 5 only
    {
        float v = t[5][tid];
        float s1, s2; block_sum2(v, v * v, red8, tid, s1, s2);
        float mu = s1 * (1.f / 256.f);
        float var = s2 * (1.f / 256.f) - mu * mu;
        tfin[(size_t)b * 256 + tid] = (v - mu) * rsqrtf(var + EPSF) * lnf_g[tid] + lnf_b[tid];
    }
}

// ---------------------------------------------------------------------------
// fin GEMM for token 5: refined5[b,n] = tfin[b,:] @ fin_w[:,n] + fin_b[n]
// M=128 (16 per block.y), N=5760 (256 per block.x), K=256
// ---------------------------------------------------------------------------
__global__ __launch_bounds__(256) void fin_gemm(const float* __restrict__ tfin,
    const float* __restrict__ fin_w, const float* __restrict__ fin_b, float* __restrict__ refined5)
{
    __shared__ float tf[16][256];
    int tid = threadIdx.x;
    int nb = blockIdx.x * 256 + tid;
    int bg = blockIdx.y * 16;
    for (int e = tid; e < 4096; e += 256) tf[e >> 8][e & 255] = tfin[(size_t)(bg + (e >> 8)) * 256 + (e & 255)];
    __syncthreads();
    if (nb < 5760) {
        float acc[16];
#pragma unroll
        for (int bb = 0; bb < 16; bb++) acc[bb] = 0.f;
        for (int k = 0; k < 256; k++) {
            float wv = fin_w[(size_t)k * 5760 + nb];
#pragma unroll
            for (int bb = 0; bb < 16; bb++) acc[bb] += tf[bb][k] * wv;
        }
        float fb = fin_b[nb];
#pragma unroll
        for (int bb = 0; bb < 16; bb++)
            refined5[(size_t)(bg + bb) * 5760 + nb] = acc[bb] + fb;
    }
}

// ---------------------------------------------------------------------------
extern "C" void kernel_launch(void* const* d_in, const int* in_sizes, int n_in,
                              void* d_out, int out_size, void* d_ws, size_t ws_size,
                              hipStream_t stream)
{
    const float* x      = (const float*)d_in[0];
    const float* ext_w1 = (const float*)d_in[1];
    const float* ext_b1 = (const float*)d_in[2];
    const float* ext_g  = (const float*)d_in[3];
    const float* ext_bb = (const float*)d_in[4];
    const float* ext_m  = (const float*)d_in[5];
    const float* ext_v  = (const float*)d_in[6];
    const float* ext_w2 = (const float*)d_in[7];
    const float* ext_b2 = (const float*)d_in[8];
    const float* cls_w1 = (const float*)d_in[9];
    const float* cls_b1 = (const float*)d_in[10];
    const float* cls_g  = (const float*)d_in[11];
    const float* cls_bb = (const float*)d_in[12];
    const float* cls_m  = (const float*)d_in[13];
    const float* cls_v  = (const float*)d_in[14];
    const float* cls_w2 = (const float*)d_in[15];
    const float* cls_b2 = (const float*)d_in[16];
    const float* tok_w  = (const float*)d_in[17];
    const float* tok_b  = (const float*)d_in[18];
    const float* emb    = (const float*)d_in[19];
    const float* ln1_g  = (const float*)d_in[20];
    const float* ln1_b  = (const float*)d_in[21];
    const float* qkv_w  = (const float*)d_in[22];
    const float* out_w  = (const float*)d_in[23];
    const float* out_b  = (const float*)d_in[24];
    const float* ln2_g  = (const float*)d_in[25];
    const float* ln2_b  = (const float*)d_in[26];
    const float* ff_w1  = (const float*)d_in[27];
    const float* ff_b1  = (const float*)d_in[28];
    const float* ff_w2  = (const float*)d_in[29];
    const float* ff_b2  = (const float*)d_in[30];
    const float* lnf_g  = (const float*)d_in[31];
    const float* lnf_b  = (const float*)d_in[32];
    const float* fin_w  = (const float*)d_in[33];
    const float* fin_b  = (const float*)d_in[34];

    float* out = (float*)d_out;
    float* ws  = (float*)d_ws;

    // workspace layout (floats)
    float* h1       = ws;                       // 18432*512   = 9437184
    float* logits   = ws + 9437184;             // 18432*144   = 2654208
    float* partials = ws + 12091392;            // 4608
    float* patches  = ws + 12096000;            // 128*5760    = 737280
    float* tokens   = ws + 12833280;            // 128*6*256   = 196608
    float* tfin     = ws + 13029888;            // 128*256     = 32768
    float* refined5 = ws + 13062656;            // 128*5760    = 737280
    float* tpart    = ws + 13799936;            // 128*8*256   = 262144
    int*   amax     = (int*)(ws + 14062080);    // 18432
    int*   flag     = (int*)(ws + 14080512);    // 1

    // output offsets: ext | cls | ext2 | cls2
    float* out_ext  = out;
    float* out_cls  = out + 36864;
    float* out_ext2 = out + 2691072;
    float* out_cls2 = out + 2727936;

    dim3 blk(256);

    // pass 1: heads_on(x)
    head1_gemm<0><<<dim3(4, 144), blk, 0, stream>>>(x, ext_w1, cls_w1,
        ext_b1, ext_g, ext_bb, ext_m, ext_v,
        cls_b1, cls_g, cls_bb, cls_m, cls_v,
        nullptr, nullptr, nullptr, h1);
    cls2_gemm<<<dim3(3, 288), blk, 0, stream>>>(h1, cls_w2, cls_b2, logits);
    cls_softmax<<<4608, blk, 0, stream>>>(logits, out_cls, amax);
    ext_head<<<4608, blk, 0, stream>>>(h1, ext_w2, ext_b2, out_ext, partials);
    reduce_flag<<<1, blk, 0, stream>>>(partials, 4608, flag);

    // refine chain (always computed; application predicated on flag)
    gather_patches<<<2880, blk, 0, stream>>>(x, amax, patches);
    tok_partial<<<dim3(128, 8), blk, 0, stream>>>(patches, tok_w, tpart);
    tok_finish<<<128, blk, 0, stream>>>(tpart, tok_b, emb, tokens);
    transformer_kernel<<<128, blk, 0, stream>>>(tokens, ln1_g, ln1_b, qkv_w, out_w, out_b,
        ln2_g, ln2_b, ff_w1, ff_b1, ff_w2, ff_b2, lnf_g, lnf_b, tfin);
    fin_gemm<<<dim3(23, 8), blk, 0, stream>>>(tfin, fin_w, fin_b, refined5);

    // pass 2: heads_on(x2), x2 patched on the fly
    head1_gemm<1><<<dim3(4, 144), blk, 0, stream>>>(x, ext_w1, cls_w1,
        ext_b1, ext_g, ext_bb, ext_m, ext_v,
        cls_b1, cls_g, cls_bb, cls_m, cls_v,
        amax, refined5, flag, h1);
    cls2_gemm<<<dim3(3, 288), blk, 0, stream>>>(h1, cls_w2, cls_b2, logits);
    cls_softmax<<<4608, blk, 0, stream>>>(logits, out_cls2, nullptr);
    ext_head<<<4608, blk, 0, stream>>>(h1, ext_w2, ext_b2, out_ext2, nullptr);
}

// Round 4
// 410.535 us; speedup vs baseline: 3.5705x; 3.5705x over previous
//
#include <hip/hip_runtime.h>
#include <math.h>

#define EPSF 1e-5f
#define GAPTH 1e-3f

// B=128, C=8, H=144, W=144, CW=1152, R=18432, TW=5, OG=2, NCLS=6, DT=256, ITC=5760
// Collapsed head: logits[row, j] = sum_k Wc[j,k] * x'[row,k] + cconst[j]
//   j 0..143 = cls, j 144..145 = ext, j 146..159 = zero pad. NP=160.

typedef __attribute__((ext_vector_type(8))) short short8v;
typedef __attribute__((ext_vector_type(4))) float f32x4;
typedef unsigned short ushort;
typedef unsigned int uint;

__device__ inline ushort f2bf(float f) {
    uint u = __float_as_uint(f);
    uint r = (u + 0x7FFFu + ((u >> 16) & 1u)) >> 16;
    return (ushort)r;
}
__device__ inline float bf2f(ushort h) { return __uint_as_float(((uint)h) << 16); }

// ---------------------------------------------------------------------------
// Build combined weights: Wc[j,k] = sum_o w2[j,o]*s[o]*w1[o,k], s = g*rsqrt(v+eps)
// cconst[j] = sum_o w2[j,o]*((b1[o]-m[o])*s[o]+bb[o]) + b2[j].  Also bf16 hi/lo.
// ---------------------------------------------------------------------------
__global__ __launch_bounds__(256) void wcomb_build(
    const float* __restrict__ w1e, const float* __restrict__ b1e, const float* __restrict__ ge,
    const float* __restrict__ bbe, const float* __restrict__ me, const float* __restrict__ ve,
    const float* __restrict__ w2e, const float* __restrict__ b2e,
    const float* __restrict__ w1c, const float* __restrict__ b1c, const float* __restrict__ gc,
    const float* __restrict__ bbc, const float* __restrict__ mc, const float* __restrict__ vc,
    const float* __restrict__ w2c, const float* __restrict__ b2c,
    float* __restrict__ Wc32, ushort* __restrict__ Wchi, ushort* __restrict__ Wclo,
    float* __restrict__ cconst)
{
    __shared__ float coef[256];
    __shared__ float csum[4];
    const int j = blockIdx.x, tid = threadIdx.x;
    const int lane = tid & 63, wid = tid >> 6;

    const float *w1 = nullptr, *w2row = nullptr, *b1 = nullptr, *g = nullptr,
                *bb = nullptr, *m = nullptr, *v = nullptr;
    float b2v = 0.f;
    int valid = 0;
    if (j < 144) {
        valid = 1; w1 = w1c; w2row = w2c + (size_t)j * 256;
        b1 = b1c; g = gc; bb = bbc; m = mc; v = vc; b2v = b2c[j];
    } else if (j < 146) {
        valid = 1; w1 = w1e; w2row = w2e + (size_t)(j - 144) * 256;
        b1 = b1e; g = ge; bb = bbe; m = me; v = ve; b2v = b2e[j - 144];
    }

    float cf = 0.f, cc = 0.f;
    if (valid) {
        float s = g[tid] * rsqrtf(v[tid] + EPSF);
        float w2v = w2row[tid];
        cf = w2v * s;
        cc = w2v * ((b1[tid] - m[tid]) * s + bb[tid]);
    }
    coef[tid] = cf;
    float t = cc;
#pragma unroll
    for (int off = 32; off; off >>= 1) t += __shfl_xor(t, off);
    if (lane == 0) csum[wid] = t;
    __syncthreads();
    if (tid == 0) cconst[j] = valid ? ((csum[0] + csum[1]) + (csum[2] + csum[3]) + b2v) : 0.f;

    for (int k = tid; k < 1152; k += 256) {
        float acc = 0.f;
        if (valid) {
            for (int o = 0; o < 256; o++) acc += coef[o] * w1[(size_t)o * 1152 + k];
        }
        Wc32[(size_t)j * 1152 + k] = acc;
        ushort hi = f2bf(acc);
        Wchi[(size_t)j * 1152 + k] = hi;
        Wclo[(size_t)j * 1152 + k] = f2bf(acc - bf2f(hi));
    }
}

// ---------------------------------------------------------------------------
// logits GEMM: M=18432, N=160(146 used), K=1152, split-bf16 MFMA (hi/lo, 3 products)
// BM=64, BN=160, BK=32; 4 waves as 2m x 2n; wave tile 32x80 (2x5 16x16 frags)
// PATCH=1: x columns in argmax window replaced by refined5 (predicated on *flag)
// ---------------------------------------------------------------------------
template<int PATCH>
__global__ __launch_bounds__(256) void logits_gemm(
    const float* __restrict__ x, const ushort* __restrict__ Wchi, const ushort* __restrict__ Wclo,
    const float* __restrict__ cconst, const int* __restrict__ amax,
    const float* __restrict__ refined5, const int* __restrict__ flag,
    float* __restrict__ logits)
{
    __shared__ ushort Ahi[64][40], Alo[64][40], Bhi[160][40], Blo[160][40];
    const int tid = threadIdx.x;
    const int lane = tid & 63, wid = tid >> 6;
    const int wm = wid & 1, wn = wid >> 1;
    const int rb = blockIdx.x * 64;

    // A staging coords (fixed per thread): 8 contiguous k per thread
    const int rl = tid >> 2, kk = (tid & 3) << 3;
    const int arow = rb + rl;
    const int ab = arow / 144, ahh = arow - ab * 144;
    int fl = 0, pa = 0;
    if (PATCH) { fl = *flag; if (fl) pa = amax[arow]; }

    // B staging coords
    const int br0 = tid >> 2, bk0 = (tid & 3) << 3;          // rows 0..63
    const int br2 = 128 + (tid >> 3), bk2 = (tid & 7) << 2;  // rows 128..159

    float av[8];
    short8v vbh0, vbl0, vbh1, vbl1;
    ushort vbh2[4], vbl2[4];

    auto LOAD = [&](int kb) {
        int k1 = kb + kk, c1 = k1 / 144, w1 = k1 - c1 * 144;
        const float4 t0 = *reinterpret_cast<const float4*>(
            x + (((size_t)(ab * 8 + c1) * 144 + ahh) * 144 + w1));
        int k2 = k1 + 4, c2 = k2 / 144, w2 = k2 - c2 * 144;
        const float4 t1 = *reinterpret_cast<const float4*>(
            x + (((size_t)(ab * 8 + c2) * 144 + ahh) * 144 + w2));
        av[0] = t0.x; av[1] = t0.y; av[2] = t0.z; av[3] = t0.w;
        av[4] = t1.x; av[5] = t1.y; av[6] = t1.z; av[7] = t1.w;
        if (PATCH && fl) {
            int d0 = w1 - pa + 2;
#pragma unroll
            for (int q = 0; q < 4; q++) {
                int dw = d0 + q;
                if (dw >= 0 && dw < 5)
                    av[q] = refined5[(size_t)ab * 5760 + (c1 * 144 + ahh) * 5 + dw];
            }
            int d1 = w2 - pa + 2;
#pragma unroll
            for (int q = 0; q < 4; q++) {
                int dw = d1 + q;
                if (dw >= 0 && dw < 5)
                    av[4 + q] = refined5[(size_t)ab * 5760 + (c2 * 144 + ahh) * 5 + dw];
            }
        }
        size_t o0 = (size_t)br0 * 1152 + kb + bk0;
        vbh0 = *reinterpret_cast<const short8v*>(Wchi + o0);
        vbl0 = *reinterpret_cast<const short8v*>(Wclo + o0);
        size_t o1 = (size_t)(br0 + 64) * 1152 + kb + bk0;
        vbh1 = *reinterpret_cast<const short8v*>(Wchi + o1);
        vbl1 = *reinterpret_cast<const short8v*>(Wclo + o1);
        size_t o2 = (size_t)br2 * 1152 + kb + bk2;
#pragma unroll
        for (int q = 0; q < 4; q++) { vbh2[q] = Wchi[o2 + q]; vbl2[q] = Wclo[o2 + q]; }
    };

    auto STORE = [&]() {
        ushort h[8], l[8];
#pragma unroll
        for (int q = 0; q < 8; q++) {
            h[q] = f2bf(av[q]);
            l[q] = f2bf(av[q] - bf2f(h[q]));
        }
#pragma unroll
        for (int q = 0; q < 8; q++) { Ahi[rl][kk + q] = h[q]; Alo[rl][kk + q] = l[q]; }
        *reinterpret_cast<short8v*>(&Bhi[br0][bk0]) = vbh0;
        *reinterpret_cast<short8v*>(&Blo[br0][bk0]) = vbl0;
        *reinterpret_cast<short8v*>(&Bhi[br0 + 64][bk0]) = vbh1;
        *reinterpret_cast<short8v*>(&Blo[br0 + 64][bk0]) = vbl1;
#pragma unroll
        for (int q = 0; q < 4; q++) { Bhi[br2][bk2 + q] = vbh2[q]; Blo[br2][bk2 + q] = vbl2[q]; }
    };

    f32x4 acc[2][5];
#pragma unroll
    for (int mt = 0; mt < 2; mt++)
#pragma unroll
        for (int nt = 0; nt < 5; nt++) acc[mt][nt] = (f32x4){0.f, 0.f, 0.f, 0.f};

    const int fr = lane & 15, fg = (lane >> 4) << 3;

    LOAD(0);
    for (int t = 0; t < 36; t++) {
        STORE();
        if (t < 35) LOAD((t + 1) * 32);
        __syncthreads();
        short8v ah0 = *reinterpret_cast<const short8v*>(&Ahi[wm * 32 + fr][fg]);
        short8v al0 = *reinterpret_cast<const short8v*>(&Alo[wm * 32 + fr][fg]);
        short8v ah1 = *reinterpret_cast<const short8v*>(&Ahi[wm * 32 + 16 + fr][fg]);
        short8v al1 = *reinterpret_cast<const short8v*>(&Alo[wm * 32 + 16 + fr][fg]);
#pragma unroll
        for (int nt = 0; nt < 5; nt++) {
            short8v bh = *reinterpret_cast<const short8v*>(&Bhi[wn * 80 + nt * 16 + fr][fg]);
            short8v bl = *reinterpret_cast<const short8v*>(&Blo[wn * 80 + nt * 16 + fr][fg]);
            acc[0][nt] = __builtin_amdgcn_mfma_f32_16x16x32_bf16(ah0, bh, acc[0][nt], 0, 0, 0);
            acc[0][nt] = __builtin_amdgcn_mfma_f32_16x16x32_bf16(ah0, bl, acc[0][nt], 0, 0, 0);
            acc[0][nt] = __builtin_amdgcn_mfma_f32_16x16x32_bf16(al0, bh, acc[0][nt], 0, 0, 0);
            acc[1][nt] = __builtin_amdgcn_mfma_f32_16x16x32_bf16(ah1, bh, acc[1][nt], 0, 0, 0);
            acc[1][nt] = __builtin_amdgcn_mfma_f32_16x16x32_bf16(ah1, bl, acc[1][nt], 0, 0, 0);
            acc[1][nt] = __builtin_amdgcn_mfma_f32_16x16x32_bf16(al1, bh, acc[1][nt], 0, 0, 0);
        }
        __syncthreads();
    }

    // epilogue: C/D layout col=lane&15, row=(lane>>4)*4+i  [m89-verified]
#pragma unroll
    for (int mt = 0; mt < 2; mt++) {
#pragma unroll
        for (int nt = 0; nt < 5; nt++) {
            int gcol = wn * 80 + nt * 16 + fr;
            if (gcol < 146) {
                float cc = cconst[gcol];
                float* dst = logits + (size_t)(rb + wm * 32 + mt * 16 + ((lane >> 4) << 2)) * 160 + gcol;
#pragma unroll
                for (int i = 0; i < 4; i++)
                    dst[(size_t)i * 160] = acc[mt][nt][i] + cc;
            }
        }
    }
}

// ---------------------------------------------------------------------------
// merged softmax: cls over cols 0..143 (+argmax pass1), ext over cols 144..145
// one wave per row, 4 rows per block
// ---------------------------------------------------------------------------
__global__ __launch_bounds__(256) void softmax_heads(
    const float* __restrict__ logits, float* __restrict__ out_cls, float* __restrict__ out_ext,
    int* __restrict__ amax, float* __restrict__ partials)
{
    __shared__ float ps[4];
    int row = blockIdx.x * 4 + (threadIdx.x >> 6);
    int lane = threadIdx.x & 63;
    const float* L = logits + (size_t)row * 160;
    float v0 = L[lane];
    float v1 = L[lane + 64];
    float v2 = (lane < 16) ? L[lane + 128] : -3.0e38f;
    float m = v0; int mi = lane;
    if (v1 > m) { m = v1; mi = lane + 64; }
    if (v2 > m) { m = v2; mi = lane + 128; }
#pragma unroll
    for (int off = 32; off; off >>= 1) {
        float om = __shfl_xor(m, off);
        int   oi = __shfl_xor(mi, off);
        if (om > m || (om == m && oi < mi)) { m = om; mi = oi; }
    }
    float e0 = expf(v0 - m), e1 = expf(v1 - m);
    float e2 = (lane < 16) ? expf(v2 - m) : 0.f;
    float s = e0 + e1 + e2;
#pragma unroll
    for (int off = 32; off; off >>= 1) s += __shfl_xor(s, off);
    float inv = 1.f / s;
    float* O = out_cls + (size_t)row * 144;
    O[lane] = e0 * inv;
    O[lane + 64] = e1 * inv;
    if (lane < 16) O[lane + 128] = e2 * inv;

    // ext head (2 logits)
    float l0 = L[144], l1 = L[145];
    float mx = fmaxf(l0, l1);
    float ee0 = expf(l0 - mx), ee1 = expf(l1 - mx);
    float einv = 1.f / (ee0 + ee1);
    float p0 = ee0 * einv;
    if (lane == 0) {
        out_ext[(size_t)row * 2] = p0;
        out_ext[(size_t)row * 2 + 1] = ee1 * einv;
        if (amax != nullptr) amax[row] = mi;
    }
    if (partials != nullptr) {
        if (lane == 0) ps[threadIdx.x >> 6] = p0;
        __syncthreads();
        if (threadIdx.x == 0) partials[blockIdx.x] = (ps[0] + ps[1]) + (ps[2] + ps[3]);
    }
}

__global__ __launch_bounds__(256) void reduce_flag(const float* __restrict__ partials, int n,
                                                   int* __restrict__ flag)
{
    __shared__ float sm[256];
    int tid = threadIdx.x;
    float s = 0.f;
    for (int i = tid; i < n; i += 256) s += partials[i];
    sm[tid] = s; __syncthreads();
    for (int off = 128; off; off >>= 1) {
        if (tid < off) sm[tid] += sm[tid + off];
        __syncthreads();
    }
    if (tid == 0) *flag = (sm[0] * (1.f / 18432.f) > 0.3f) ? 1 : 0;
}

// ---------------------------------------------------------------------------
// argmax fixup: rows with MFMA top-2 gap < GAPTH get exact f32 two-stage recompute
// (mirrors reference order: h1 = w1c@row + b1c -> BN -> w2c@h + b2c -> argmax)
// ---------------------------------------------------------------------------
__global__ __launch_bounds__(256) void argmax_fixup(
    const float* __restrict__ logits, const float* __restrict__ x,
    const float* __restrict__ w1c, const float* __restrict__ b1c,
    const float* __restrict__ gc, const float* __restrict__ bbc,
    const float* __restrict__ mc, const float* __restrict__ vc,
    const float* __restrict__ w2c, const float* __restrict__ b2c,
    int* __restrict__ amax)
{
    __shared__ float red[2];
    __shared__ float xrow[1152];
    __shared__ float hsh[256];
    __shared__ float Lsh[144];
    const int row = blockIdx.x, tid = threadIdx.x;

    if (tid < 64) {
        const float* L = logits + (size_t)row * 160;
        float v0 = L[tid], v1 = L[tid + 64];
        float v2 = (tid < 16) ? L[tid + 128] : -3.0e38f;
        float m1 = v0, m2 = -3.0e38f;
        if (v1 > m1) { m2 = m1; m1 = v1; } else m2 = v1;
        if (v2 > m1) { m2 = m1; m1 = v2; } else m2 = fmaxf(m2, v2);
#pragma unroll
        for (int off = 32; off; off >>= 1) {
            float om1 = __shfl_xor(m1, off);
            float om2 = __shfl_xor(m2, off);
            float nm1 = fmaxf(m1, om1);
            m2 = fmaxf(fminf(m1, om1), fmaxf(m2, om2));
            m1 = nm1;
        }
        if (tid == 0) { red[0] = m1; red[1] = m2; }
    }
    __syncthreads();
    if (red[0] - red[1] >= GAPTH) return;

    // exact recompute for this row
    const int b = row / 144, hh = row - b * 144;
    for (int e = tid; e < 1152; e += 256) {
        int c = e / 144, w = e - c * 144;
        xrow[e] = x[(((size_t)(b * 8 + c) * 144 + hh) * 144) + w];
    }
    __syncthreads();
    {
        const float* wr = w1c + (size_t)tid * 1152;
        float d = b1c[tid];
#pragma unroll 4
        for (int k = 0; k < 1152; k++) d += wr[k] * xrow[k];
        float s = gc[tid] * rsqrtf(vc[tid] + EPSF);
        hsh[tid] = (d - mc[tid]) * s + bbc[tid];
    }
    __syncthreads();
    if (tid < 144) {
        const float* wr = w2c + (size_t)tid * 256;
        float d = b2c[tid];
#pragma unroll 4
        for (int k = 0; k < 256; k++) d += wr[k] * hsh[k];
        Lsh[tid] = d;
    }
    __syncthreads();
    if (tid == 0) {
        int bi = 0; float bv = Lsh[0];
        for (int j = 1; j < 144; j++) if (Lsh[j] > bv) { bv = Lsh[j]; bi = j; }
        amax[row] = bi;
    }
}

// ---------------------------------------------------------------------------
// gather patches from zero-padded x at argmax windows
// ---------------------------------------------------------------------------
__global__ __launch_bounds__(256) void gather_patches(const float* __restrict__ x,
    const int* __restrict__ amax, float* __restrict__ patches)
{
    int idx = blockIdx.x * 256 + threadIdx.x;
    int b = idx / 5760, j = idx - b * 5760;
    int c = j / 720, r2 = j - c * 720;
    int hh = r2 / 5, tw = r2 - hh * 5;
    int a = amax[b * 144 + hh];
    int w = a + tw - 2;
    patches[idx] = (w >= 0 && w < 144) ? x[(((size_t)(b * 8 + c) * 144 + hh) * 144) + w] : 0.f;
}

// ---------------------------------------------------------------------------
// tok GEMM, K-split into 8 chunks of 720 (deterministic 2-stage)
// ---------------------------------------------------------------------------
__global__ __launch_bounds__(256) void tok_partial(const float* __restrict__ patches,
    const float* __restrict__ tok_w, float* __restrict__ tpart)
{
    __shared__ float P[720];
    int b = blockIdx.x, ks = blockIdx.y, tid = threadIdx.x;
    for (int e = tid; e < 720; e += 256) P[e] = patches[(size_t)b * 5760 + ks * 720 + e];
    __syncthreads();
    float acc = 0.f;
    const float* wbase = tok_w + (size_t)ks * 720 * 256;
    for (int k = 0; k < 720; k++) acc += P[k] * wbase[(size_t)k * 256 + tid];
    tpart[((size_t)b * 8 + ks) * 256 + tid] = acc;
}

__global__ __launch_bounds__(256) void tok_finish(const float* __restrict__ tpart,
    const float* __restrict__ tok_b, const float* __restrict__ emb, float* __restrict__ tokens)
{
    int b = blockIdx.x, n = threadIdx.x;
    float s = tok_b[n];
    for (int ks = 0; ks < 8; ks++) s += tpart[((size_t)b * 8 + ks) * 256 + n];
    for (int i = 0; i < 6; i++) tokens[((size_t)b * 6 + i) * 256 + n] = s + emb[i * 256 + n];
}

// ---------------------------------------------------------------------------
// tiny transformer per batch element (seq=6, dim=256, 2 heads x 32); LNF of token 5
// ---------------------------------------------------------------------------
__device__ inline void block_sum2(float v1, float v2, float* r8, int tid, float& s1, float& s2)
{
#pragma unroll
    for (int off = 32; off; off >>= 1) { v1 += __shfl_down(v1, off); v2 += __shfl_down(v2, off); }
    int w = tid >> 6;
    if ((tid & 63) == 0) { r8[w * 2] = v1; r8[w * 2 + 1] = v2; }
    __syncthreads();
    s1 = (r8[0] + r8[2]) + (r8[4] + r8[6]);
    s2 = (r8[1] + r8[3]) + (r8[5] + r8[7]);
    __syncthreads();
}

__global__ __launch_bounds__(256) void transformer_kernel(
    const float* __restrict__ tokens,
    const float* __restrict__ ln1_g, const float* __restrict__ ln1_b,
    const float* __restrict__ qkv_w, const float* __restrict__ out_w, const float* __restrict__ out_b,
    const float* __restrict__ ln2_g, const float* __restrict__ ln2_b,
    const float* __restrict__ ff_w1, const float* __restrict__ ff_b1,
    const float* __restrict__ ff_w2, const float* __restrict__ ff_b2,
    const float* __restrict__ lnf_g, const float* __restrict__ lnf_b,
    float* __restrict__ tfin)
{
    __shared__ float t[6][256];
    __shared__ float z[6][256];
    __shared__ float qkv[6][192];
    __shared__ float att[2][6][6];
    __shared__ float o[6][64];
    __shared__ float f[6][512];
    __shared__ float red8[8];

    int b = blockIdx.x, tid = threadIdx.x;
    for (int e = tid; e < 1536; e += 256) t[e >> 8][e & 255] = tokens[(size_t)b * 1536 + e];
    __syncthreads();

    for (int i = 0; i < 6; i++) {
        float v = t[i][tid];
        float s1, s2; block_sum2(v, v * v, red8, tid, s1, s2);
        float mu = s1 * (1.f / 256.f);
        float var = s2 * (1.f / 256.f) - mu * mu;
        z[i][tid] = (v - mu) * rsqrtf(var + EPSF) * ln1_g[tid] + ln1_b[tid];
    }
    __syncthreads();

    if (tid < 192) {
        float acc[6] = {0.f, 0.f, 0.f, 0.f, 0.f, 0.f};
        for (int k = 0; k < 256; k++) {
            float wv = qkv_w[(size_t)k * 192 + tid];
#pragma unroll
            for (int i = 0; i < 6; i++) acc[i] += z[i][k] * wv;
        }
#pragma unroll
        for (int i = 0; i < 6; i++) qkv[i][tid] = acc[i];
    }
    __syncthreads();

    if (tid < 72) {
        int h = tid / 36, rem = tid - h * 36, i = rem / 6, j = rem - (rem / 6) * 6;
        float s = 0.f;
#pragma unroll
        for (int d = 0; d < 32; d++) s += qkv[i][h * 32 + d] * qkv[j][64 + h * 32 + d];
        att[h][i][j] = s * 0.17677669529663687f;
    }
    __syncthreads();
    if (tid < 12) {
        int h = tid / 6, i = tid - h * 6;
        float m = -3.0e38f;
        for (int j = 0; j < 6; j++) m = fmaxf(m, att[h][i][j]);
        float s = 0.f;
        for (int j = 0; j < 6; j++) { float e = expf(att[h][i][j] - m); att[h][i][j] = e; s += e; }
        float inv = 1.f / s;
        for (int j = 0; j < 6; j++) att[h][i][j] *= inv;
    }
    __syncthreads();
    for (int e = tid; e < 384; e += 256) {
        int i = e / 64, hd = e - i * 64, h = hd >> 5;
        float s = 0.f;
#pragma unroll
        for (int j = 0; j < 6; j++) s += att[h][i][j] * qkv[j][128 + hd];
        o[i][hd] = s;
    }
    __syncthreads();
    {
        float accs[6];
#pragma unroll
        for (int i = 0; i < 6; i++) {
            float a = out_b[tid];
            for (int d = 0; d < 64; d++) a += o[i][d] * out_w[(size_t)d * 256 + tid];
            accs[i] = a;
        }
#pragma unroll
        for (int i = 0; i < 6; i++) t[i][tid] += accs[i];
    }
    __syncthreads();

    for (int i = 0; i < 6; i++) {
        float v = t[i][tid];
        float s1, s2; block_sum2(v, v * v, red8, tid, s1, s2);
        float mu = s1 * (1.f / 256.f);
        float var = s2 * (1.f / 256.f) - mu * mu;
        z[i][tid] = (v - mu) * rsqrtf(var + EPSF) * ln2_g[tid] + ln2_b[tid];
    }
    __syncthreads();

    for (int jj = tid; jj < 512; jj += 256) {
        float acc[6] = {0.f, 0.f, 0.f, 0.f, 0.f, 0.f};
        for (int k = 0; k < 256; k++) {
            float wv = ff_w1[(size_t)k * 512 + jj];
#pragma unroll
            for (int i = 0; i < 6; i++) acc[i] += z[i][k] * wv;
        }
#pragma unroll
        for (int i = 0; i < 6; i++) {
            float xx = acc[i] + ff_b1[jj];
            f[i][jj] = 0.5f * xx * (1.f + erff(xx * 0.70710678118654752f));
        }
    }
    __syncthreads();
    {
        float a6[6];
#pragma unroll
        for (int i = 0; i < 6; i++) a6[i] = ff_b2[tid];
        for (int k = 0; k < 512; k++) {
            float wv = ff_w2[(size_t)k * 256 + tid];
#pragma unroll
            for (int i = 0; i < 6; i++) a6[i] += f[i][k] * wv;
        }
#pragma unroll
        for (int i = 0; i < 6; i++) t[i][tid] += a6[i];
    }
    __syncthreads();

    {
        float v = t[5][tid];
        float s1, s2; block_sum2(v, v * v, red8, tid, s1, s2);
        float mu = s1 * (1.f / 256.f);
        float var = s2 * (1.f / 256.f) - mu * mu;
        tfin[(size_t)b * 256 + tid] = (v - mu) * rsqrtf(var + EPSF) * lnf_g[tid] + lnf_b[tid];
    }
}

// ---------------------------------------------------------------------------
// fin GEMM for token 5: refined5[b,n] = tfin[b,:] @ fin_w[:,n] + fin_b[n]
// ---------------------------------------------------------------------------
__global__ __launch_bounds__(256) void fin_gemm(const float* __restrict__ tfin,
    const float* __restrict__ fin_w, const float* __restrict__ fin_b, float* __restrict__ refined5)
{
    __shared__ float tf[16][256];
    int tid = threadIdx.x;
    int nb = blockIdx.x * 256 + tid;
    int bg = blockIdx.y * 16;
    for (int e = tid; e < 4096; e += 256) tf[e >> 8][e & 255] = tfin[(size_t)(bg + (e >> 8)) * 256 + (e & 255)];
    __syncthreads();
    if (nb < 5760) {
        float acc[16];
#pragma unroll
        for (int bb = 0; bb < 16; bb++) acc[bb] = 0.f;
        for (int k = 0; k < 256; k++) {
            float wv = fin_w[(size_t)k * 5760 + nb];
#pragma unroll
            for (int bb = 0; bb < 16; bb++) acc[bb] += tf[bb][k] * wv;
        }
        float fb = fin_b[nb];
#pragma unroll
        for (int bb = 0; bb < 16; bb++)
            refined5[(size_t)(bg + bb) * 5760 + nb] = acc[bb] + fb;
    }
}

// ---------------------------------------------------------------------------
extern "C" void kernel_launch(void* const* d_in, const int* in_sizes, int n_in,
                              void* d_out, int out_size, void* d_ws, size_t ws_size,
                              hipStream_t stream)
{
    const float* x      = (const float*)d_in[0];
    const float* ext_w1 = (const float*)d_in[1];
    const float* ext_b1 = (const float*)d_in[2];
    const float* ext_g  = (const float*)d_in[3];
    const float* ext_bb = (const float*)d_in[4];
    const float* ext_m  = (const float*)d_in[5];
    const float* ext_v  = (const float*)d_in[6];
    const float* ext_w2 = (const float*)d_in[7];
    const float* ext_b2 = (const float*)d_in[8];
    const float* cls_w1 = (const float*)d_in[9];
    const float* cls_b1 = (const float*)d_in[10];
    const float* cls_g  = (const float*)d_in[11];
    const float* cls_bb = (const float*)d_in[12];
    const float* cls_m  = (const float*)d_in[13];
    const float* cls_v  = (const float*)d_in[14];
    const float* cls_w2 = (const float*)d_in[15];
    const float* cls_b2 = (const float*)d_in[16];
    const float* tok_w  = (const float*)d_in[17];
    const float* tok_b  = (const float*)d_in[18];
    const float* emb    = (const float*)d_in[19];
    const float* ln1_g  = (const float*)d_in[20];
    const float* ln1_b  = (const float*)d_in[21];
    const float* qkv_w  = (const float*)d_in[22];
    const float* out_w  = (const float*)d_in[23];
    const float* out_b  = (const float*)d_in[24];
    const float* ln2_g  = (const float*)d_in[25];
    const float* ln2_b  = (const float*)d_in[26];
    const float* ff_w1  = (const float*)d_in[27];
    const float* ff_b1  = (const float*)d_in[28];
    const float* ff_w2  = (const float*)d_in[29];
    const float* ff_b2  = (const float*)d_in[30];
    const float* lnf_g  = (const float*)d_in[31];
    const float* lnf_b  = (const float*)d_in[32];
    const float* fin_w  = (const float*)d_in[33];
    const float* fin_b  = (const float*)d_in[34];

    float* out = (float*)d_out;
    float* ws  = (float*)d_ws;

    // workspace layout (float offsets)
    float*  Wc32    = ws;                       // 160*1152 = 184320
    float*  cconst  = ws + 184320;              // 160
    ushort* Wchi    = (ushort*)(ws + 184480);   // 184320 ushorts
    ushort* Wclo    = (ushort*)(ws + 276640);   // 184320 ushorts
    float*  logits  = ws + 368800;              // 18432*160 = 2949120
    float*  partials= ws + 3317920;             // 4608
    float*  patches = ws + 3322528;             // 737280
    float*  tokens  = ws + 4059808;             // 196608
    float*  tfin    = ws + 4256416;             // 32768
    float*  refined5= ws + 4289184;             // 737280
    float*  tpart   = ws + 5026464;             // 262144
    int*    amax    = (int*)(ws + 5288608);     // 18432
    int*    flag    = (int*)(ws + 5307040);     // 1

    // output offsets: ext | cls | ext2 | cls2
    float* out_ext  = out;
    float* out_cls  = out + 36864;
    float* out_ext2 = out + 2691072;
    float* out_cls2 = out + 2727936;

    dim3 blk(256);

    // combined weights (independent of x)
    wcomb_build<<<160, blk, 0, stream>>>(
        ext_w1, ext_b1, ext_g, ext_bb, ext_m, ext_v, ext_w2, ext_b2,
        cls_w1, cls_b1, cls_g, cls_bb, cls_m, cls_v, cls_w2, cls_b2,
        Wc32, Wchi, Wclo, cconst);

    // pass 1
    logits_gemm<0><<<288, blk, 0, stream>>>(x, Wchi, Wclo, cconst,
        nullptr, nullptr, nullptr, logits);
    softmax_heads<<<4608, blk, 0, stream>>>(logits, out_cls, out_ext, amax, partials);
    reduce_flag<<<1, blk, 0, stream>>>(partials, 4608, flag);
    argmax_fixup<<<18432, blk, 0, stream>>>(logits, x,
        cls_w1, cls_b1, cls_g, cls_bb, cls_m, cls_v, cls_w2, cls_b2, amax);

    // refine chain (always computed; application predicated on flag)
    gather_patches<<<2880, blk, 0, stream>>>(x, amax, patches);
    tok_partial<<<dim3(128, 8), blk, 0, stream>>>(patches, tok_w, tpart);
    tok_finish<<<128, blk, 0, stream>>>(tpart, tok_b, emb, tokens);
    transformer_kernel<<<128, blk, 0, stream>>>(tokens, ln1_g, ln1_b, qkv_w, out_w, out_b,
        ln2_g, ln2_b, ff_w1, ff_b1, ff_w2, ff_b2, lnf_g, lnf_b, tfin);
    fin_gemm<<<dim3(23, 8), blk, 0, stream>>>(tfin, fin_w, fin_b, refined5);

    // pass 2 (x2 patched on the fly)
    logits_gemm<1><<<288, blk, 0, stream>>>(x, Wchi, Wclo, cconst,
        amax, refined5, flag, logits);
    softmax_heads<<<4608, blk, 0, stream>>>(logits, out_cls2, out_ext2, nullptr, nullptr);
}

// Round 5
// 396.854 us; speedup vs baseline: 3.6936x; 1.0345x over previous
//
#include <hip/hip_runtime.h>
#include <math.h>

#define EPSF 1e-5f
#define GAPTH 1e-3f

// B=128, C=8, H=144, W=144, CW=1152, R=18432, TW=5, OG=2, NCLS=6, DT=256, ITC=5760
// Collapsed head: logits[row, j] = sum_k Wc[j,k] * x'[row,k] + cconst[j]
//   j 0..143 = cls, j 144..145 = ext, j 146..159 = zero pad. NP=160.

typedef __attribute__((ext_vector_type(8))) short short8v;
typedef __attribute__((ext_vector_type(4))) float f32x4;
typedef unsigned short ushort;
typedef unsigned int uint;

__device__ inline ushort f2bf(float f) {
    uint u = __float_as_uint(f);
    uint r = (u + 0x7FFFu + ((u >> 16) & 1u)) >> 16;
    return (ushort)r;
}
__device__ inline float bf2f(ushort h) { return __uint_as_float(((uint)h) << 16); }

// ---------------------------------------------------------------------------
// Build combined weights: Wc[j,k] = sum_o w2[j,o]*s[o]*w1[o,k], s = g*rsqrt(v+eps)
// cconst[j] = sum_o w2[j,o]*((b1[o]-m[o])*s[o]+bb[o]) + b2[j].  Also bf16 hi/lo.
// ---------------------------------------------------------------------------
__global__ __launch_bounds__(256) void wcomb_build(
    const float* __restrict__ w1e, const float* __restrict__ b1e, const float* __restrict__ ge,
    const float* __restrict__ bbe, const float* __restrict__ me, const float* __restrict__ ve,
    const float* __restrict__ w2e, const float* __restrict__ b2e,
    const float* __restrict__ w1c, const float* __restrict__ b1c, const float* __restrict__ gc,
    const float* __restrict__ bbc, const float* __restrict__ mc, const float* __restrict__ vc,
    const float* __restrict__ w2c, const float* __restrict__ b2c,
    float* __restrict__ Wc32, ushort* __restrict__ Wchi, ushort* __restrict__ Wclo,
    float* __restrict__ cconst)
{
    __shared__ float coef[256];
    __shared__ float csum[4];
    const int j = blockIdx.x, tid = threadIdx.x;
    const int lane = tid & 63, wid = tid >> 6;

    const float *w1 = nullptr, *w2row = nullptr, *b1 = nullptr, *g = nullptr,
                *bb = nullptr, *m = nullptr, *v = nullptr;
    float b2v = 0.f;
    int valid = 0;
    if (j < 144) {
        valid = 1; w1 = w1c; w2row = w2c + (size_t)j * 256;
        b1 = b1c; g = gc; bb = bbc; m = mc; v = vc; b2v = b2c[j];
    } else if (j < 146) {
        valid = 1; w1 = w1e; w2row = w2e + (size_t)(j - 144) * 256;
        b1 = b1e; g = ge; bb = bbe; m = me; v = ve; b2v = b2e[j - 144];
    }

    float cf = 0.f, cc = 0.f;
    if (valid) {
        float s = g[tid] * rsqrtf(v[tid] + EPSF);
        float w2v = w2row[tid];
        cf = w2v * s;
        cc = w2v * ((b1[tid] - m[tid]) * s + bb[tid]);
    }
    coef[tid] = cf;
    float t = cc;
#pragma unroll
    for (int off = 32; off; off >>= 1) t += __shfl_xor(t, off);
    if (lane == 0) csum[wid] = t;
    __syncthreads();
    if (tid == 0) cconst[j] = valid ? ((csum[0] + csum[1]) + (csum[2] + csum[3]) + b2v) : 0.f;

    for (int k = tid; k < 1152; k += 256) {
        float acc = 0.f;
        if (valid) {
            for (int o = 0; o < 256; o++) acc += coef[o] * w1[(size_t)o * 1152 + k];
        }
        Wc32[(size_t)j * 1152 + k] = acc;
        ushort hi = f2bf(acc);
        Wchi[(size_t)j * 1152 + k] = hi;
        Wclo[(size_t)j * 1152 + k] = f2bf(acc - bf2f(hi));
    }
}

__global__ void zero_counters(int* __restrict__ cand_count)
{
    *cand_count = 0;
}

// ---------------------------------------------------------------------------
// logits GEMM: M=18432, N=160(146 used), K=1152, split-bf16 MFMA (hi/lo, 3 products)
// BM=64, BN=160, BK=32; 4 waves as 2m x 2n; wave tile 32x80 (2x5 16x16 frags)
// PATCH=1: x columns in argmax window replaced by refined5 (predicated on *flag)
// ---------------------------------------------------------------------------
template<int PATCH>
__global__ __launch_bounds__(256) void logits_gemm(
    const float* __restrict__ x, const ushort* __restrict__ Wchi, const ushort* __restrict__ Wclo,
    const float* __restrict__ cconst, const int* __restrict__ amax,
    const float* __restrict__ refined5, const int* __restrict__ flag,
    float* __restrict__ logits)
{
    __shared__ ushort Ahi[64][40], Alo[64][40], Bhi[160][40], Blo[160][40];
    const int tid = threadIdx.x;
    const int lane = tid & 63, wid = tid >> 6;
    const int wm = wid & 1, wn = wid >> 1;
    const int rb = blockIdx.x * 64;

    // A staging coords (fixed per thread): 8 contiguous k per thread
    const int rl = tid >> 2, kk = (tid & 3) << 3;
    const int arow = rb + rl;
    const int ab = arow / 144, ahh = arow - ab * 144;
    int fl = 0, pa = 0;
    if (PATCH) { fl = *flag; if (fl) pa = amax[arow]; }

    // B staging coords
    const int br0 = tid >> 2, bk0 = (tid & 3) << 3;          // rows 0..63
    const int br2 = 128 + (tid >> 3), bk2 = (tid & 7) << 2;  // rows 128..159

    float av[8];
    short8v vbh0, vbl0, vbh1, vbl1;
    ushort vbh2[4], vbl2[4];

    auto LOAD = [&](int kb) {
        int k1 = kb + kk, c1 = k1 / 144, w1 = k1 - c1 * 144;
        const float4 t0 = *reinterpret_cast<const float4*>(
            x + (((size_t)(ab * 8 + c1) * 144 + ahh) * 144 + w1));
        int k2 = k1 + 4, c2 = k2 / 144, w2 = k2 - c2 * 144;
        const float4 t1 = *reinterpret_cast<const float4*>(
            x + (((size_t)(ab * 8 + c2) * 144 + ahh) * 144 + w2));
        av[0] = t0.x; av[1] = t0.y; av[2] = t0.z; av[3] = t0.w;
        av[4] = t1.x; av[5] = t1.y; av[6] = t1.z; av[7] = t1.w;
        if (PATCH && fl) {
            int d0 = w1 - pa + 2;
#pragma unroll
            for (int q = 0; q < 4; q++) {
                int dw = d0 + q;
                if (dw >= 0 && dw < 5)
                    av[q] = refined5[(size_t)ab * 5760 + (c1 * 144 + ahh) * 5 + dw];
            }
            int d1 = w2 - pa + 2;
#pragma unroll
            for (int q = 0; q < 4; q++) {
                int dw = d1 + q;
                if (dw >= 0 && dw < 5)
                    av[4 + q] = refined5[(size_t)ab * 5760 + (c2 * 144 + ahh) * 5 + dw];
            }
        }
        size_t o0 = (size_t)br0 * 1152 + kb + bk0;
        vbh0 = *reinterpret_cast<const short8v*>(Wchi + o0);
        vbl0 = *reinterpret_cast<const short8v*>(Wclo + o0);
        size_t o1 = (size_t)(br0 + 64) * 1152 + kb + bk0;
        vbh1 = *reinterpret_cast<const short8v*>(Wchi + o1);
        vbl1 = *reinterpret_cast<const short8v*>(Wclo + o1);
        size_t o2 = (size_t)br2 * 1152 + kb + bk2;
#pragma unroll
        for (int q = 0; q < 4; q++) { vbh2[q] = Wchi[o2 + q]; vbl2[q] = Wclo[o2 + q]; }
    };

    auto STORE = [&]() {
        ushort h[8], l[8];
#pragma unroll
        for (int q = 0; q < 8; q++) {
            h[q] = f2bf(av[q]);
            l[q] = f2bf(av[q] - bf2f(h[q]));
        }
#pragma unroll
        for (int q = 0; q < 8; q++) { Ahi[rl][kk + q] = h[q]; Alo[rl][kk + q] = l[q]; }
        *reinterpret_cast<short8v*>(&Bhi[br0][bk0]) = vbh0;
        *reinterpret_cast<short8v*>(&Blo[br0][bk0]) = vbl0;
        *reinterpret_cast<short8v*>(&Bhi[br0 + 64][bk0]) = vbh1;
        *reinterpret_cast<short8v*>(&Blo[br0 + 64][bk0]) = vbl1;
#pragma unroll
        for (int q = 0; q < 4; q++) { Bhi[br2][bk2 + q] = vbh2[q]; Blo[br2][bk2 + q] = vbl2[q]; }
    };

    f32x4 acc[2][5];
#pragma unroll
    for (int mt = 0; mt < 2; mt++)
#pragma unroll
        for (int nt = 0; nt < 5; nt++) acc[mt][nt] = (f32x4){0.f, 0.f, 0.f, 0.f};

    const int fr = lane & 15, fg = (lane >> 4) << 3;

    LOAD(0);
    for (int t = 0; t < 36; t++) {
        STORE();
        if (t < 35) LOAD((t + 1) * 32);
        __syncthreads();
        short8v ah0 = *reinterpret_cast<const short8v*>(&Ahi[wm * 32 + fr][fg]);
        short8v al0 = *reinterpret_cast<const short8v*>(&Alo[wm * 32 + fr][fg]);
        short8v ah1 = *reinterpret_cast<const short8v*>(&Ahi[wm * 32 + 16 + fr][fg]);
        short8v al1 = *reinterpret_cast<const short8v*>(&Alo[wm * 32 + 16 + fr][fg]);
#pragma unroll
        for (int nt = 0; nt < 5; nt++) {
            short8v bh = *reinterpret_cast<const short8v*>(&Bhi[wn * 80 + nt * 16 + fr][fg]);
            short8v bl = *reinterpret_cast<const short8v*>(&Blo[wn * 80 + nt * 16 + fr][fg]);
            acc[0][nt] = __builtin_amdgcn_mfma_f32_16x16x32_bf16(ah0, bh, acc[0][nt], 0, 0, 0);
            acc[0][nt] = __builtin_amdgcn_mfma_f32_16x16x32_bf16(ah0, bl, acc[0][nt], 0, 0, 0);
            acc[0][nt] = __builtin_amdgcn_mfma_f32_16x16x32_bf16(al0, bh, acc[0][nt], 0, 0, 0);
            acc[1][nt] = __builtin_amdgcn_mfma_f32_16x16x32_bf16(ah1, bh, acc[1][nt], 0, 0, 0);
            acc[1][nt] = __builtin_amdgcn_mfma_f32_16x16x32_bf16(ah1, bl, acc[1][nt], 0, 0, 0);
            acc[1][nt] = __builtin_amdgcn_mfma_f32_16x16x32_bf16(al1, bh, acc[1][nt], 0, 0, 0);
        }
        __syncthreads();
    }

    // epilogue: C/D layout col=lane&15, row=(lane>>4)*4+i  [m89-verified]
#pragma unroll
    for (int mt = 0; mt < 2; mt++) {
#pragma unroll
        for (int nt = 0; nt < 5; nt++) {
            int gcol = wn * 80 + nt * 16 + fr;
            if (gcol < 146) {
                float cc = cconst[gcol];
                float* dst = logits + (size_t)(rb + wm * 32 + mt * 16 + ((lane >> 4) << 2)) * 160 + gcol;
#pragma unroll
                for (int i = 0; i < 4; i++)
                    dst[(size_t)i * 160] = acc[mt][nt][i] + cc;
            }
        }
    }
}

// ---------------------------------------------------------------------------
// merged softmax: cls over cols 0..143 (+argmax & top-2 gap -> candidate list),
// ext over cols 144..145.  One wave per row, 4 rows per block.
// ---------------------------------------------------------------------------
__global__ __launch_bounds__(256) void softmax_heads(
    const float* __restrict__ logits, float* __restrict__ out_cls, float* __restrict__ out_ext,
    int* __restrict__ amax, float* __restrict__ partials,
    int* __restrict__ cand_count, int* __restrict__ cand_list)
{
    __shared__ float ps[4];
    int row = blockIdx.x * 4 + (threadIdx.x >> 6);
    int lane = threadIdx.x & 63;
    const float* L = logits + (size_t)row * 160;
    float v0 = L[lane];
    float v1 = L[lane + 64];
    float v2 = (lane < 16) ? L[lane + 128] : -3.0e38f;
    // argmax (first-max tie rule) + top-2 values
    float m = v0; int mi = lane;
    if (v1 > m) { m = v1; mi = lane + 64; }
    if (v2 > m) { m = v2; mi = lane + 128; }
    float m1 = v0, m2 = -3.0e38f;
    if (v1 > m1) { m2 = m1; m1 = v1; } else m2 = v1;
    if (v2 > m1) { m2 = m1; m1 = v2; } else m2 = fmaxf(m2, v2);
#pragma unroll
    for (int off = 32; off; off >>= 1) {
        float om = __shfl_xor(m, off);
        int   oi = __shfl_xor(mi, off);
        if (om > m || (om == m && oi < mi)) { m = om; mi = oi; }
        float om1 = __shfl_xor(m1, off);
        float om2 = __shfl_xor(m2, off);
        float nm1 = fmaxf(m1, om1);
        m2 = fmaxf(fminf(m1, om1), fmaxf(m2, om2));
        m1 = nm1;
    }
    float e0 = expf(v0 - m), e1 = expf(v1 - m);
    float e2 = (lane < 16) ? expf(v2 - m) : 0.f;
    float s = e0 + e1 + e2;
#pragma unroll
    for (int off = 32; off; off >>= 1) s += __shfl_xor(s, off);
    float inv = 1.f / s;
    float* O = out_cls + (size_t)row * 144;
    O[lane] = e0 * inv;
    O[lane + 64] = e1 * inv;
    if (lane < 16) O[lane + 128] = e2 * inv;

    // ext head (2 logits)
    float l0 = L[144], l1 = L[145];
    float mx = fmaxf(l0, l1);
    float ee0 = expf(l0 - mx), ee1 = expf(l1 - mx);
    float einv = 1.f / (ee0 + ee1);
    float p0 = ee0 * einv;
    if (lane == 0) {
        out_ext[(size_t)row * 2] = p0;
        out_ext[(size_t)row * 2 + 1] = ee1 * einv;
        if (amax != nullptr) {
            amax[row] = mi;
            if (m1 - m2 < GAPTH) {
                int slot = atomicAdd(cand_count, 1);
                cand_list[slot] = row;
            }
        }
    }
    if (partials != nullptr) {
        if (lane == 0) ps[threadIdx.x >> 6] = p0;
        __syncthreads();
        if (threadIdx.x == 0) partials[blockIdx.x] = (ps[0] + ps[1]) + (ps[2] + ps[3]);
    }
}

__global__ __launch_bounds__(256) void reduce_flag(const float* __restrict__ partials, int n,
                                                   int* __restrict__ flag)
{
    __shared__ float sm[256];
    int tid = threadIdx.x;
    float s = 0.f;
    for (int i = tid; i < n; i += 256) s += partials[i];
    sm[tid] = s; __syncthreads();
    for (int off = 128; off; off >>= 1) {
        if (tid < off) sm[tid] += sm[tid + off];
        __syncthreads();
    }
    if (tid == 0) *flag = (sm[0] * (1.f / 18432.f) > 0.3f) ? 1 : 0;
}

// ---------------------------------------------------------------------------
// fixup over compacted candidate list: exact f32 two-stage recompute of argmax
// (mirrors reference order). Coalesced: per wave, lane-strided k + butterfly.
// ---------------------------------------------------------------------------
__global__ __launch_bounds__(256) void fixup_list(
    const int* __restrict__ cand_count, const int* __restrict__ cand_list,
    const float* __restrict__ x,
    const float* __restrict__ w1c, const float* __restrict__ b1c,
    const float* __restrict__ gc, const float* __restrict__ bbc,
    const float* __restrict__ mc, const float* __restrict__ vc,
    const float* __restrict__ w2c, const float* __restrict__ b2c,
    int* __restrict__ amax)
{
    __shared__ float xrow[1152];
    __shared__ float hsh[256];
    __shared__ float Lsh[144];
    const int tid = threadIdx.x;
    const int lane = tid & 63, wid = tid >> 6;
    const int n = *cand_count;

    for (int ci = blockIdx.x; ci < n; ci += gridDim.x) {
        const int row = cand_list[ci];
        const int b = row / 144, hh = row - b * 144;
        for (int e = tid; e < 1152; e += 256) {
            int c = e / 144, w = e - c * 144;
            xrow[e] = x[(((size_t)(b * 8 + c) * 144 + hh) * 144) + w];
        }
        __syncthreads();
        // stage 1: h[o] = dot(w1c[o,:], xrow) -> BN.  wave wid handles o in [wid*64, +64)
        for (int oo = 0; oo < 64; oo++) {
            int o = wid * 64 + oo;
            const float* wr = w1c + (size_t)o * 1152;
            float a = 0.f;
#pragma unroll
            for (int j = 0; j < 18; j++) a += wr[lane + 64 * j] * xrow[lane + 64 * j];
#pragma unroll
            for (int off = 32; off; off >>= 1) a += __shfl_xor(a, off);
            if (lane == 0) {
                float sc = gc[o] * rsqrtf(vc[o] + EPSF);
                hsh[o] = (a + b1c[o] - mc[o]) * sc + bbc[o];
            }
        }
        __syncthreads();
        // stage 2: L[j] = dot(w2c[j,:], h) + b2c[j].  wave wid handles j in [wid*36, +36)
        for (int jj = 0; jj < 36; jj++) {
            int j = wid * 36 + jj;
            const float* wr = w2c + (size_t)j * 256;
            float a = wr[lane] * hsh[lane] + wr[lane + 64] * hsh[lane + 64]
                    + wr[lane + 128] * hsh[lane + 128] + wr[lane + 192] * hsh[lane + 192];
#pragma unroll
            for (int off = 32; off; off >>= 1) a += __shfl_xor(a, off);
            if (lane == 0) Lsh[j] = a + b2c[j];
        }
        __syncthreads();
        if (tid == 0) {
            int bi = 0; float bv = Lsh[0];
            for (int j = 1; j < 144; j++) if (Lsh[j] > bv) { bv = Lsh[j]; bi = j; }
            amax[row] = bi;
        }
        __syncthreads();
    }
}

// ---------------------------------------------------------------------------
// gather patches from zero-padded x at argmax windows
// ---------------------------------------------------------------------------
__global__ __launch_bounds__(256) void gather_patches(const float* __restrict__ x,
    const int* __restrict__ amax, float* __restrict__ patches)
{
    int idx = blockIdx.x * 256 + threadIdx.x;
    int b = idx / 5760, j = idx - b * 5760;
    int c = j / 720, r2 = j - c * 720;
    int hh = r2 / 5, tw = r2 - hh * 5;
    int a = amax[b * 144 + hh];
    int w = a + tw - 2;
    patches[idx] = (w >= 0 && w < 144) ? x[(((size_t)(b * 8 + c) * 144 + hh) * 144) + w] : 0.f;
}

// ---------------------------------------------------------------------------
// tok GEMM, K-split into 8 chunks of 720 (deterministic 2-stage)
// ---------------------------------------------------------------------------
__global__ __launch_bounds__(256) void tok_partial(const float* __restrict__ patches,
    const float* __restrict__ tok_w, float* __restrict__ tpart)
{
    __shared__ float P[720];
    int b = blockIdx.x, ks = blockIdx.y, tid = threadIdx.x;
    for (int e = tid; e < 720; e += 256) P[e] = patches[(size_t)b * 5760 + ks * 720 + e];
    __syncthreads();
    float acc = 0.f;
    const float* wbase = tok_w + (size_t)ks * 720 * 256;
    for (int k = 0; k < 720; k++) acc += P[k] * wbase[(size_t)k * 256 + tid];
    tpart[((size_t)b * 8 + ks) * 256 + tid] = acc;
}

__global__ __launch_bounds__(256) void tok_finish(const float* __restrict__ tpart,
    const float* __restrict__ tok_b, const float* __restrict__ emb, float* __restrict__ tokens)
{
    int b = blockIdx.x, n = threadIdx.x;
    float s = tok_b[n];
    for (int ks = 0; ks < 8; ks++) s += tpart[((size_t)b * 8 + ks) * 256 + n];
    for (int i = 0; i < 6; i++) tokens[((size_t)b * 6 + i) * 256 + n] = s + emb[i * 256 + n];
}

// ---------------------------------------------------------------------------
// tiny transformer per batch element (seq=6, dim=256, 2 heads x 32); LNF of token 5
// ---------------------------------------------------------------------------
__device__ inline void block_sum2(float v1, float v2, float* r8, int tid, float& s1, float& s2)
{
#pragma unroll
    for (int off = 32; off; off >>= 1) { v1 += __shfl_down(v1, off); v2 += __shfl_down(v2, off); }
    int w = tid >> 6;
    if ((tid & 63) == 0) { r8[w * 2] = v1; r8[w * 2 + 1] = v2; }
    __syncthreads();
    s1 = (r8[0] + r8[2]) + (r8[4] + r8[6]);
    s2 = (r8[1] + r8[3]) + (r8[5] + r8[7]);
    __syncthreads();
}

__global__ __launch_bounds__(256) void transformer_kernel(
    const float* __restrict__ tokens,
    const float* __restrict__ ln1_g, const float* __restrict__ ln1_b,
    const float* __restrict__ qkv_w, const float* __restrict__ out_w, const float* __restrict__ out_b,
    const float* __restrict__ ln2_g, const float* __restrict__ ln2_b,
    const float* __restrict__ ff_w1, const float* __restrict__ ff_b1,
    const float* __restrict__ ff_w2, const float* __restrict__ ff_b2,
    const float* __restrict__ lnf_g, const float* __restrict__ lnf_b,
    float* __restrict__ tfin)
{
    __shared__ float t[6][256];
    __shared__ float z[6][256];
    __shared__ float qkv[6][192];
    __shared__ float att[2][6][6];
    __shared__ float o[6][64];
    __shared__ float f[6][512];
    __shared__ float red8[8];

    int b = blockIdx.x, tid = threadIdx.x;
    for (int e = tid; e < 1536; e += 256) t[e >> 8][e & 255] = tokens[(size_t)b * 1536 + e];
    __syncthreads();

    for (int i = 0; i < 6; i++) {
        float v = t[i][tid];
        float s1, s2; block_sum2(v, v * v, red8, tid, s1, s2);
        float mu = s1 * (1.f / 256.f);
        float var = s2 * (1.f / 256.f) - mu * mu;
        z[i][tid] = (v - mu) * rsqrtf(var + EPSF) * ln1_g[tid] + ln1_b[tid];
    }
    __syncthreads();

    if (tid < 192) {
        float acc[6] = {0.f, 0.f, 0.f, 0.f, 0.f, 0.f};
        for (int k = 0; k < 256; k++) {
            float wv = qkv_w[(size_t)k * 192 + tid];
#pragma unroll
            for (int i = 0; i < 6; i++) acc[i] += z[i][k] * wv;
        }
#pragma unroll
        for (int i = 0; i < 6; i++) qkv[i][tid] = acc[i];
    }
    __syncthreads();

    if (tid < 72) {
        int h = tid / 36, rem = tid - h * 36, i = rem / 6, j = rem - (rem / 6) * 6;
        float s = 0.f;
#pragma unroll
        for (int d = 0; d < 32; d++) s += qkv[i][h * 32 + d] * qkv[j][64 + h * 32 + d];
        att[h][i][j] = s * 0.17677669529663687f;
    }
    __syncthreads();
    if (tid < 12) {
        int h = tid / 6, i = tid - h * 6;
        float m = -3.0e38f;
        for (int j = 0; j < 6; j++) m = fmaxf(m, att[h][i][j]);
        float s = 0.f;
        for (int j = 0; j < 6; j++) { float e = expf(att[h][i][j] - m); att[h][i][j] = e; s += e; }
        float inv = 1.f / s;
        for (int j = 0; j < 6; j++) att[h][i][j] *= inv;
    }
    __syncthreads();
    for (int e = tid; e < 384; e += 256) {
        int i = e / 64, hd = e - i * 64, h = hd >> 5;
        float s = 0.f;
#pragma unroll
        for (int j = 0; j < 6; j++) s += att[h][i][j] * qkv[j][128 + hd];
        o[i][hd] = s;
    }
    __syncthreads();
    {
        float accs[6];
#pragma unroll
        for (int i = 0; i < 6; i++) {
            float a = out_b[tid];
            for (int d = 0; d < 64; d++) a += o[i][d] * out_w[(size_t)d * 256 + tid];
            accs[i] = a;
        }
#pragma unroll
        for (int i = 0; i < 6; i++) t[i][tid] += accs[i];
    }
    __syncthreads();

    for (int i = 0; i < 6; i++) {
        float v = t[i][tid];
        float s1, s2; block_sum2(v, v * v, red8, tid, s1, s2);
        float mu = s1 * (1.f / 256.f);
        float var = s2 * (1.f / 256.f) - mu * mu;
        z[i][tid] = (v - mu) * rsqrtf(var + EPSF) * ln2_g[tid] + ln2_b[tid];
    }
    __syncthreads();

    for (int jj = tid; jj < 512; jj += 256) {
        float acc[6] = {0.f, 0.f, 0.f, 0.f, 0.f, 0.f};
        for (int k = 0; k < 256; k++) {
            float wv = ff_w1[(size_t)k * 512 + jj];
#pragma unroll
            for (int i = 0; i < 6; i++) acc[i] += z[i][k] * wv;
        }
#pragma unroll
        for (int i = 0; i < 6; i++) {
            float xx = acc[i] + ff_b1[jj];
            f[i][jj] = 0.5f * xx * (1.f + erff(xx * 0.70710678118654752f));
        }
    }
    __syncthreads();
    {
        float a6[6];
#pragma unroll
        for (int i = 0; i < 6; i++) a6[i] = ff_b2[tid];
        for (int k = 0; k < 512; k++) {
            float wv = ff_w2[(size_t)k * 256 + tid];
#pragma unroll
            for (int i = 0; i < 6; i++) a6[i] += f[i][k] * wv;
        }
#pragma unroll
        for (int i = 0; i < 6; i++) t[i][tid] += a6[i];
    }
    __syncthreads();

    {
        float v = t[5][tid];
        float s1, s2; block_sum2(v, v * v, red8, tid, s1, s2);
        float mu = s1 * (1.f / 256.f);
        float var = s2 * (1.f / 256.f) - mu * mu;
        tfin[(size_t)b * 256 + tid] = (v - mu) * rsqrtf(var + EPSF) * lnf_g[tid] + lnf_b[tid];
    }
}

// ---------------------------------------------------------------------------
// fin GEMM for token 5: refined5[b,n] = tfin[b,:] @ fin_w[:,n] + fin_b[n]
// ---------------------------------------------------------------------------
__global__ __launch_bounds__(256) void fin_gemm(const float* __restrict__ tfin,
    const float* __restrict__ fin_w, const float* __restrict__ fin_b, float* __restrict__ refined5)
{
    __shared__ float tf[16][256];
    int tid = threadIdx.x;
    int nb = blockIdx.x * 256 + tid;
    int bg = blockIdx.y * 16;
    for (int e = tid; e < 4096; e += 256) tf[e >> 8][e & 255] = tfin[(size_t)(bg + (e >> 8)) * 256 + (e & 255)];
    __syncthreads();
    if (nb < 5760) {
        float acc[16];
#pragma unroll
        for (int bb = 0; bb < 16; bb++) acc[bb] = 0.f;
        for (int k = 0; k < 256; k++) {
            float wv = fin_w[(size_t)k * 5760 + nb];
#pragma unroll
            for (int bb = 0; bb < 16; bb++) acc[bb] += tf[bb][k] * wv;
        }
        float fb = fin_b[nb];
#pragma unroll
        for (int bb = 0; bb < 16; bb++)
            refined5[(size_t)(bg + bb) * 5760 + nb] = acc[bb] + fb;
    }
}

// ---------------------------------------------------------------------------
extern "C" void kernel_launch(void* const* d_in, const int* in_sizes, int n_in,
                              void* d_out, int out_size, void* d_ws, size_t ws_size,
                              hipStream_t stream)
{
    const float* x      = (const float*)d_in[0];
    const float* ext_w1 = (const float*)d_in[1];
    const float* ext_b1 = (const float*)d_in[2];
    const float* ext_g  = (const float*)d_in[3];
    const float* ext_bb = (const float*)d_in[4];
    const float* ext_m  = (const float*)d_in[5];
    const float* ext_v  = (const float*)d_in[6];
    const float* ext_w2 = (const float*)d_in[7];
    const float* ext_b2 = (const float*)d_in[8];
    const float* cls_w1 = (const float*)d_in[9];
    const float* cls_b1 = (const float*)d_in[10];
    const float* cls_g  = (const float*)d_in[11];
    const float* cls_bb = (const float*)d_in[12];
    const float* cls_m  = (const float*)d_in[13];
    const float* cls_v  = (const float*)d_in[14];
    const float* cls_w2 = (const float*)d_in[15];
    const float* cls_b2 = (const float*)d_in[16];
    const float* tok_w  = (const float*)d_in[17];
    const float* tok_b  = (const float*)d_in[18];
    const float* emb    = (const float*)d_in[19];
    const float* ln1_g  = (const float*)d_in[20];
    const float* ln1_b  = (const float*)d_in[21];
    const float* qkv_w  = (const float*)d_in[22];
    const float* out_w  = (const float*)d_in[23];
    const float* out_b  = (const float*)d_in[24];
    const float* ln2_g  = (const float*)d_in[25];
    const float* ln2_b  = (const float*)d_in[26];
    const float* ff_w1  = (const float*)d_in[27];
    const float* ff_b1  = (const float*)d_in[28];
    const float* ff_w2  = (const float*)d_in[29];
    const float* ff_b2  = (const float*)d_in[30];
    const float* lnf_g  = (const float*)d_in[31];
    const float* lnf_b  = (const float*)d_in[32];
    const float* fin_w  = (const float*)d_in[33];
    const float* fin_b  = (const float*)d_in[34];

    float* out = (float*)d_out;
    float* ws  = (float*)d_ws;

    // workspace layout (float offsets)
    float*  Wc32     = ws;                       // 160*1152 = 184320
    float*  cconst   = ws + 184320;              // 160
    ushort* Wchi     = (ushort*)(ws + 184480);   // 184320 ushorts
    ushort* Wclo     = (ushort*)(ws + 276640);   // 184320 ushorts
    float*  logits   = ws + 368800;              // 18432*160 = 2949120
    float*  partials = ws + 3317920;             // 4608
    float*  patches  = ws + 3322528;             // 737280
    float*  tokens   = ws + 4059808;             // 196608
    float*  tfin     = ws + 4256416;             // 32768
    float*  refined5 = ws + 4289184;             // 737280
    float*  tpart    = ws + 5026464;             // 262144
    int*    amax     = (int*)(ws + 5288608);     // 18432
    int*    flag     = (int*)(ws + 5307040);     // 1
    int*    cand_cnt = (int*)(ws + 5307041);     // 1
    int*    cand_lst = (int*)(ws + 5307042);     // 18432

    // output offsets: ext | cls | ext2 | cls2
    float* out_ext  = out;
    float* out_cls  = out + 36864;
    float* out_ext2 = out + 2691072;
    float* out_cls2 = out + 2727936;

    dim3 blk(256);

    // combined weights (independent of x)
    wcomb_build<<<160, blk, 0, stream>>>(
        ext_w1, ext_b1, ext_g, ext_bb, ext_m, ext_v, ext_w2, ext_b2,
        cls_w1, cls_b1, cls_g, cls_bb, cls_m, cls_v, cls_w2, cls_b2,
        Wc32, Wchi, Wclo, cconst);
    zero_counters<<<1, 1, 0, stream>>>(cand_cnt);

    // pass 1
    logits_gemm<0><<<288, blk, 0, stream>>>(x, Wchi, Wclo, cconst,
        nullptr, nullptr, nullptr, logits);
    softmax_heads<<<4608, blk, 0, stream>>>(logits, out_cls, out_ext, amax, partials,
        cand_cnt, cand_lst);
    reduce_flag<<<1, blk, 0, stream>>>(partials, 4608, flag);
    fixup_list<<<256, blk, 0, stream>>>(cand_cnt, cand_lst, x,
        cls_w1, cls_b1, cls_g, cls_bb, cls_m, cls_v, cls_w2, cls_b2, amax);

    // refine chain (always computed; application predicated on flag)
    gather_patches<<<2880, blk, 0, stream>>>(x, amax, patches);
    tok_partial<<<dim3(128, 8), blk, 0, stream>>>(patches, tok_w, tpart);
    tok_finish<<<128, blk, 0, stream>>>(tpart, tok_b, emb, tokens);
    transformer_kernel<<<128, blk, 0, stream>>>(tokens, ln1_g, ln1_b, qkv_w, out_w, out_b,
        ln2_g, ln2_b, ff_w1, ff_b1, ff_w2, ff_b2, lnf_g, lnf_b, tfin);
    fin_gemm<<<dim3(23, 8), blk, 0, stream>>>(tfin, fin_w, fin_b, refined5);

    // pass 2 (x2 patched on the fly)
    logits_gemm<1><<<288, blk, 0, stream>>>(x, Wchi, Wclo, cconst,
        amax, refined5, flag, logits);
    softmax_heads<<<4608, blk, 0, stream>>>(logits, out_cls2, out_ext2, nullptr, nullptr,
        nullptr, nullptr);
}